// Round 3
// baseline (209.159 us; speedup 1.0000x reference)
//
#include <hip/hip_runtime.h>
#include <cstddef>

#define NUM_TYPES    4
#define NUM_SPLINES  16
#define NUM_CHANNELS 64
#define PAD_LO       5               // rows cover s in [-5 .. 21]
#define NROWS        27
#define ROW_U32      32              // 64 bf16 channels = 32 u32
#define CLS_STRIDE   (NROWS * ROW_U32)     // 864 u32 per class
#define LDS_U32      (16 * CLS_STRIDE)     // 13824 u32 = 55296 B

// cos(2*pi*r) via hardware v_cos; |r| < 0.5 always here (no range reduction).
__device__ __forceinline__ float cos_rev(float r) {
    float o;
    asm("v_cos_f32 %0, %1" : "=v"(o) : "v"(r));
    return o;
}

// round-to-nearest-even f32 -> bf16, packed pair (a=low16, b=high16)
__device__ __forceinline__ unsigned pack_bf16(float a, float b) {
    unsigned ua = __float_as_uint(a);
    unsigned ub = __float_as_uint(b);
    ua += 0x7fffu + ((ua >> 16) & 1u);
    ub += 0x7fffu + ((ub >> 16) & 1u);
    return (ua >> 16) | (ub & 0xffff0000u);
}
__device__ __forceinline__ float bf_lo(unsigned w) { return __uint_as_float(w << 16); }
__device__ __forceinline__ float bf_hi(unsigned w) { return __uint_as_float(w & 0xffff0000u); }

__global__ __launch_bounds__(512, 4)
void spline_embed_kernel(const int* __restrict__ atom_types,
                         const int* __restrict__ edge_src,
                         const int* __restrict__ edge_dst,
                         const float* __restrict__ norm_length,
                         const float* __restrict__ class_weight,
                         float* __restrict__ out,
                         int n_edges)
{
    __shared__ __align__(16) unsigned lds_w[LDS_U32];

    // ---- zero entire table (covers the zero pad rows) ----
    for (int i = threadIdx.x; i < LDS_U32; i += blockDim.x) lds_w[i] = 0u;
    __syncthreads();

    // ---- fill real rows s=0..15 at row index s+PAD_LO (bf16x2 packed) ----
    {
        const float2* src = reinterpret_cast<const float2*>(class_weight);
        for (int j = threadIdx.x; j < 16 * NUM_SPLINES * (NUM_CHANNELS / 2); j += blockDim.x) {
            float2 v = src[j];
            const int cls = j >> 9;        // 512 float2 per class
            const int rem = j & 511;
            const int s   = rem >> 5;      // 32 float2 per spline row
            const int col = rem & 31;
            lds_w[cls * CLS_STRIDE + (s + PAD_LO) * ROW_U32 + col] = pack_bf16(v.x, v.y);
        }
    }
    __syncthreads();

    const int lane = threadIdx.x & 63;
    const int g    = lane >> 3;          // 8-lane group 0..7 (edge within step)
    const int cl   = lane & 7;           // channel octet: channels cl*8 .. cl*8+7

    const int waves_per_block = blockDim.x >> 6;
    const int gwave  = blockIdx.x * waves_per_block + (threadIdx.x >> 6);
    const int nwaves = gridDim.x * waves_per_block;
    const int nchunks = (n_edges + 63) >> 6;   // 64 edges per wave-chunk

    for (int chunk = gwave; chunk < nchunks; chunk += nwaves) {
        const int e0 = chunk << 6;

        // ---- coalesced metadata load: lane handles edge e0+lane ----
        int   et_m = 0;
        float t_m  = 0.0f;
        {
            const int em = e0 + lane;
            if (em < n_edges) {
                const int i0 = edge_src[em];
                const int i1 = edge_dst[em];
                et_m = atom_types[i0] * NUM_TYPES + atom_types[i1];
                t_m  = norm_length[em] * 15.0f;   // t = x/h, h = 1/15
            }
        }

        // ---- 8 steps x 8 edges; NO unroll (keep VGPR < 128, no spills) ----
        #pragma unroll 1
        for (int k = 0; k < 8; ++k) {
            const int idx  = (k << 3) + g;          // edge index within chunk
            const int e    = e0 + idx;
            const int et_e = __shfl(et_m, idx);
            const float t  = __shfl(t_m, idx);

            // window: 12 taps from slo = floor(t)-5 (UNCLAMPED, in [-5,10]).
            // All taps satisfy |u|<=1 (cos^2 -> 0 at the boundary) and
            // out-of-range splines hit the zero pad rows -> no cmp/select.
            const int slo = (int)t - 5;
            const float bu = (t - (float)slo) * (1.0f / 24.0f);   // in [5/24, 6/24]

            const unsigned* wb =
                &lds_w[et_e * CLS_STRIDE + (slo + PAD_LO) * ROW_U32 + (cl << 2)];

            float a0 = 0.f, a1 = 0.f, a2 = 0.f, a3 = 0.f;
            float a4 = 0.f, a5 = 0.f, a6 = 0.f, a7 = 0.f;
            #pragma unroll
            for (int i = 0; i < 12; ++i) {
                const float u4 = bu - (float)i * (1.0f / 24.0f);  // |u4| <= 0.25
                const float c  = cos_rev(u4);
                const float b  = c * c;
                const uint4 w  = *reinterpret_cast<const uint4*>(wb + (i << 5));
                a0 = fmaf(b, bf_lo(w.x), a0);
                a1 = fmaf(b, bf_hi(w.x), a1);
                a2 = fmaf(b, bf_lo(w.y), a2);
                a3 = fmaf(b, bf_hi(w.y), a3);
                a4 = fmaf(b, bf_lo(w.z), a4);
                a5 = fmaf(b, bf_hi(w.z), a5);
                a6 = fmaf(b, bf_lo(w.w), a6);
                a7 = fmaf(b, bf_hi(w.w), a7);
            }

            if (e < n_edges) {
                float* po = out + (size_t)e * NUM_CHANNELS + (cl << 3);
                float4 o0 = {a0, a1, a2, a3};
                float4 o1 = {a4, a5, a6, a7};
                *reinterpret_cast<float4*>(po)     = o0;
                *reinterpret_cast<float4*>(po + 4) = o1;
            }
        }
    }
}

extern "C" void kernel_launch(void* const* d_in, const int* in_sizes, int n_in,
                              void* d_out, int out_size, void* d_ws, size_t ws_size,
                              hipStream_t stream)
{
    const int*   atom_types   = (const int*)d_in[0];
    const int*   edge_index   = (const int*)d_in[1];
    const float* norm_length  = (const float*)d_in[2];
    const float* class_weight = (const float*)d_in[3];
    float*       out          = (float*)d_out;

    const int n_edges  = in_sizes[2];            // |norm_length| = E
    const int* edge_src = edge_index;            // row 0 of [2, E]
    const int* edge_dst = edge_index + n_edges;  // row 1

    dim3 block(512);
    dim3 grid(1954);   // 15632 waves -> ~2 chunks/wave over 31250 chunks
    hipLaunchKernelGGL(spline_embed_kernel, grid, block, 0, stream,
                       atom_types, edge_src, edge_dst, norm_length,
                       class_weight, out, n_edges);
}

// Round 4
// 207.680 us; speedup vs baseline: 1.0071x; 1.0071x over previous
//
#include <hip/hip_runtime.h>
#include <cstddef>

#define NUM_TYPES    4
#define NUM_SPLINES  16
#define NUM_CHANNELS 64
#define PAD_LO       5                 // row index = s + 5; rows cover s in [-5..26]
#define NROWS        32                // power-of-2 class stride -> shift addressing
#define ROW_U32      32                // 64 bf16 channels = 32 u32 = 128 B
#define CLS_SHIFT    10                // 32 rows * 32 u32 = 1024 u32 per class
#define LDS_U32      (16 << CLS_SHIFT) // 16384 u32 = 64 KB

// cos(2*pi*r) via hardware v_cos; |r| <= 0.25 here (no range reduction).
__device__ __forceinline__ float cos_rev(float r) {
    float o;
    asm("v_cos_f32 %0, %1" : "=v"(o) : "v"(r));
    return o;
}

// round-to-nearest-even f32 -> bf16, packed pair (a=low16, b=high16)
__device__ __forceinline__ unsigned pack_bf16(float a, float b) {
    unsigned ua = __float_as_uint(a);
    unsigned ub = __float_as_uint(b);
    ua += 0x7fffu + ((ua >> 16) & 1u);
    ub += 0x7fffu + ((ub >> 16) & 1u);
    return (ua >> 16) | (ub & 0xffff0000u);
}
__device__ __forceinline__ float bf_lo(unsigned w) { return __uint_as_float(w << 16); }
__device__ __forceinline__ float bf_hi(unsigned w) { return __uint_as_float(w & 0xffff0000u); }

__global__ __launch_bounds__(512, 4)
void spline_embed_kernel(const int* __restrict__ atom_types,
                         const int* __restrict__ edge_src,
                         const int* __restrict__ edge_dst,
                         const float* __restrict__ norm_length,
                         const float* __restrict__ class_weight,
                         float* __restrict__ out,
                         int n_edges)
{
    __shared__ __align__(16) unsigned lds_w[LDS_U32];     // 64 KB padded weight table
    __shared__ __align__(16) uint2    lds_meta[8 * 64];   // 4 KB, wave-private rows

    // ---- zero table (pad rows), then fill real rows s=0..15 at s+PAD_LO ----
    {
        uint4* p = reinterpret_cast<uint4*>(lds_w);
        for (int i = threadIdx.x; i < LDS_U32 / 4; i += blockDim.x)
            p[i] = uint4{0u, 0u, 0u, 0u};
    }
    __syncthreads();
    {
        const float2* src = reinterpret_cast<const float2*>(class_weight);
        for (int j = threadIdx.x; j < 16 * NUM_SPLINES * (NUM_CHANNELS / 2); j += blockDim.x) {
            float2 v = src[j];
            const int cls = j >> 9;        // 512 float2 per class
            const int rem = j & 511;
            const int s   = rem >> 5;      // 32 float2 per spline row
            const int col = rem & 31;
            lds_w[(cls << CLS_SHIFT) + ((s + PAD_LO) << 5) + col] = pack_bf16(v.x, v.y);
        }
    }
    __syncthreads();

    const int lane  = threadIdx.x & 63;
    const int g     = lane >> 3;          // 8-lane group: edge within step
    const int cl    = lane & 7;           // channel octet: channels cl*8 .. cl*8+7
    const int wbase = (threadIdx.x >> 6) << 6;   // this wave's meta row

    const int waves_per_block = blockDim.x >> 6;
    const int gwave  = blockIdx.x * waves_per_block + (threadIdx.x >> 6);
    const int nwaves = gridDim.x * waves_per_block;
    const int nchunks = (n_edges + 63) >> 6;     // 64 edges per wave-chunk

    for (int chunk = gwave; chunk < nchunks; chunk += nwaves) {
        const int e0 = chunk << 6;

        // ---- per-chunk metadata prologue: lane gathers its OWN edge, once ----
        {
            const int em = e0 + lane;
            uint2 mv = {0u, 0u};
            if (em < n_edges) {
                const int i0 = edge_src[em];
                const int i1 = edge_dst[em];
                const int et = atom_types[i0] * NUM_TYPES + atom_types[i1];
                mv.x = (unsigned)et;
                mv.y = __float_as_uint(norm_length[em] * 15.0f);  // t = x/h
            }
            lds_meta[wbase + lane] = mv;   // wave-private: no __syncthreads needed
        }

        // ---- 8 steps x 8 edges; unroll 2 for cross-step ILP ----
        #pragma unroll 2
        for (int k = 0; k < 8; ++k) {
            // broadcast read issued FIRST: in-order LDS completion means its
            // wait does NOT drain this step's weight reads.
            const uint2 m  = lds_meta[wbase + (k << 3) + g];
            const int   e  = e0 + (k << 3) + g;
            const int   et = (int)m.x;
            const float t  = __uint_as_float(m.y);

            // 12 taps from slo = floor(t)-5 (UNCLAMPED, in [-5,10]).
            // |u|<=1 over all taps (cos^2 -> 0 at boundary); out-of-range
            // splines hit zero pad rows -> no cmp/select in the tap loop.
            const int   slo = (int)t - 5;
            const float bu  = (t - (float)slo) * (1.0f / 24.0f);

            const unsigned* wb =
                &lds_w[(et << CLS_SHIFT) + ((slo + PAD_LO) << 5) + (cl << 2)];

            float a0 = 0.f, a1 = 0.f, a2 = 0.f, a3 = 0.f;
            float a4 = 0.f, a5 = 0.f, a6 = 0.f, a7 = 0.f;
            #pragma unroll
            for (int i = 0; i < 12; ++i) {
                const float u4 = bu - (float)i * (1.0f / 24.0f);  // |u4| <= 0.25
                const float c  = cos_rev(u4);
                const float b  = c * c;
                const uint4 w  = *reinterpret_cast<const uint4*>(wb + (i << 5));
                a0 = fmaf(b, bf_lo(w.x), a0);
                a1 = fmaf(b, bf_hi(w.x), a1);
                a2 = fmaf(b, bf_lo(w.y), a2);
                a3 = fmaf(b, bf_hi(w.y), a3);
                a4 = fmaf(b, bf_lo(w.z), a4);
                a5 = fmaf(b, bf_hi(w.z), a5);
                a6 = fmaf(b, bf_lo(w.w), a6);
                a7 = fmaf(b, bf_hi(w.w), a7);
            }

            if (e < n_edges) {
                float* po = out + (size_t)e * NUM_CHANNELS + (cl << 3);
                float4 o0 = {a0, a1, a2, a3};
                float4 o1 = {a4, a5, a6, a7};
                *reinterpret_cast<float4*>(po)     = o0;
                *reinterpret_cast<float4*>(po + 4) = o1;
            }
        }
    }
}

extern "C" void kernel_launch(void* const* d_in, const int* in_sizes, int n_in,
                              void* d_out, int out_size, void* d_ws, size_t ws_size,
                              hipStream_t stream)
{
    const int*   atom_types   = (const int*)d_in[0];
    const int*   edge_index   = (const int*)d_in[1];
    const float* norm_length  = (const float*)d_in[2];
    const float* class_weight = (const float*)d_in[3];
    float*       out          = (float*)d_out;

    const int n_edges  = in_sizes[2];            // |norm_length| = E
    const int* edge_src = edge_index;            // row 0 of [2, E]
    const int* edge_dst = edge_index + n_edges;  // row 1

    dim3 block(512);
    dim3 grid(1954);   // ~2 chunks per wave over 31250 chunks
    hipLaunchKernelGGL(spline_embed_kernel, grid, block, 0, stream,
                       atom_types, edge_src, edge_dst, norm_length,
                       class_weight, out, n_edges);
}

// Round 5
// 192.692 us; speedup vs baseline: 1.0855x; 1.0778x over previous
//
#include <hip/hip_runtime.h>
#include <cstddef>

#define NUM_TYPES 4
#define NUM_CH    64
#define TBL_ROWS  256          // 16 classes x 16 slo values (slo in [-5..10])
#define ROW_F32   192          // [T0(64) | TC(64) | TS(64)]
#define TBL_F32   (TBL_ROWS * ROW_F32)   // 49152 floats = 192 KB

// ---- kernel 1: build the factorized table T[cls][slo+5] = {T0, TC, TS} ----
// b_s(t) = cos^2(pi/2 * (t-s)/6) = 1/2 + 1/2*cos(theta - i*pi/6),
// theta = pi*(t-slo)/6, for the 12 in-window taps i=0..11 (|u|<=1 always).
// => out = T0 + cos(theta)*TC + sin(theta)*TS with
//    T0 = 1/2 Sum_i W[cls,slo+i,:],  TC = 1/2 Sum_i cos(i pi/6) W,  TS likewise.
__global__ void build_table_kernel(const float* __restrict__ W,
                                   float* __restrict__ T)
{
    const float COS6[12] = {1.f, 0.8660254038f, 0.5f, 0.f, -0.5f, -0.8660254038f,
                            -1.f, -0.8660254038f, -0.5f, 0.f, 0.5f, 0.8660254038f};
    const float SIN6[12] = {0.f, 0.5f, 0.8660254038f, 1.f, 0.8660254038f, 0.5f,
                            0.f, -0.5f, -0.8660254038f, -1.f, -0.8660254038f, -0.5f};
    const int gid = blockIdx.x * blockDim.x + threadIdx.x;
    if (gid >= TBL_ROWS * NUM_CH) return;
    const int c   = gid & 63;
    const int row = gid >> 6;
    const int slo = (row & 15) - 5;
    const int cls = row >> 4;

    float s0 = 0.f, sc = 0.f, ss = 0.f;
    #pragma unroll
    for (int i = 0; i < 12; ++i) {
        const int s = slo + i;
        if (s >= 0 && s < 16) {
            const float w = W[((cls << 4) + s) * NUM_CH + c];
            s0 += w;
            sc = fmaf(w, COS6[i], sc);
            ss = fmaf(w, SIN6[i], ss);
        }
    }
    float* r = T + row * ROW_F32;
    r[c]        = 0.5f * s0;
    r[64 + c]   = 0.5f * sc;
    r[128 + c]  = 0.5f * ss;
}

// ---- kernel 2: per-edge evaluation — 3 L2 reads + 8 fma + 2 trans ----
__global__ __launch_bounds__(256, 6)
void spline_embed_kernel(const int* __restrict__ atom_types,
                         const int* __restrict__ edge_src,
                         const int* __restrict__ edge_dst,
                         const float* __restrict__ norm_length,
                         const float4* __restrict__ tbl,   // table as float4
                         float* __restrict__ out,
                         int n_edges)
{
    const int lane = threadIdx.x & 63;
    const int g    = lane >> 4;          // 4 edges per step
    const int q    = lane & 15;          // channel quad: channels q*4..q*4+3

    const int waves_per_block = blockDim.x >> 6;
    const int gwave  = blockIdx.x * waves_per_block + (threadIdx.x >> 6);
    const int nwaves = gridDim.x * waves_per_block;
    const int nchunks = (n_edges + 63) >> 6;

    for (int chunk = gwave; chunk < nchunks; chunk += nwaves) {
        const int e0 = chunk << 6;

        // coalesced per-lane metadata gather (own edge)
        int   et = 0;
        float tt = 0.f;
        {
            const int em = e0 + lane;
            if (em < n_edges) {
                et = atom_types[edge_src[em]] * NUM_TYPES + atom_types[edge_dst[em]];
                tt = norm_length[em] * 15.0f;       // t = x/h, h = 1/15
            }
        }

        #pragma unroll 4
        for (int k = 0; k < 16; ++k) {
            const int idx = (k << 2) + g;
            const int e   = e0 + idx;
            const int ete = __shfl(et, idx);
            const float t = __shfl(tt, idx);

            const int   slo = (int)t - 5;                    // in [-5..10]
            const float r   = (t - (float)slo) * (1.0f / 12.0f);  // theta in revs
            float cs, sn;
            asm("v_cos_f32 %0, %1" : "=v"(cs) : "v"(r));
            asm("v_sin_f32 %0, %1" : "=v"(sn) : "v"(r));

            // row = cls*16 + (slo+5); 48 float4 per row
            const float4* rp = tbl + (((ete << 4) + slo + 5) * 48 + q);
            const float4 a = rp[0];     // T0
            const float4 b = rp[16];    // TC
            const float4 c = rp[32];    // TS

            float4 o;
            o.x = fmaf(sn, c.x, fmaf(cs, b.x, a.x));
            o.y = fmaf(sn, c.y, fmaf(cs, b.y, a.y));
            o.z = fmaf(sn, c.z, fmaf(cs, b.z, a.z));
            o.w = fmaf(sn, c.w, fmaf(cs, b.w, a.w));

            if (e < n_edges)
                *reinterpret_cast<float4*>(out + (size_t)e * NUM_CH + (q << 2)) = o;
        }
    }
}

extern "C" void kernel_launch(void* const* d_in, const int* in_sizes, int n_in,
                              void* d_out, int out_size, void* d_ws, size_t ws_size,
                              hipStream_t stream)
{
    const int*   atom_types   = (const int*)d_in[0];
    const int*   edge_index   = (const int*)d_in[1];
    const float* norm_length  = (const float*)d_in[2];
    const float* class_weight = (const float*)d_in[3];
    float*       out          = (float*)d_out;

    const int n_edges   = in_sizes[2];           // |norm_length| = E
    const int* edge_src = edge_index;            // row 0 of [2, E]
    const int* edge_dst = edge_index + n_edges;  // row 1

    float* tbl = (float*)d_ws;                   // 192 KB scratch table

    hipLaunchKernelGGL(build_table_kernel, dim3(64), dim3(256), 0, stream,
                       class_weight, tbl);

    hipLaunchKernelGGL(spline_embed_kernel, dim3(4096), dim3(256), 0, stream,
                       atom_types, edge_src, edge_dst, norm_length,
                       (const float4*)tbl, out, n_edges);
}

// Round 7
// 118.697 us; speedup vs baseline: 1.7621x; 1.6234x over previous
//
#include <hip/hip_runtime.h>
#include <cstddef>

#define NUM_TYPES 4
#define NUM_CH    64
#define TBL_ROWS  256                    // 16 classes x 16 slo values (slo in [-5..10])
#define ROW_F32   192                    // [T0(64) | TC(64) | TS(64)]

typedef float  vfloat4 __attribute__((ext_vector_type(4)));   // native vec for nt-store

// ---- kernel 1: factorized table T[cls][slo+5] = {T0, TC, TS} ----
// b_s(t) = cos^2(pi/2*(t-s)/6) = 1/2 + 1/2*cos(theta - i*pi/6), theta = pi*(t-slo)/6
// => out = T0 + cos(theta)*TC + sin(theta)*TS
__global__ void build_table_kernel(const float* __restrict__ W,
                                   float* __restrict__ T)
{
    const float COS6[12] = {1.f, 0.8660254038f, 0.5f, 0.f, -0.5f, -0.8660254038f,
                            -1.f, -0.8660254038f, -0.5f, 0.f, 0.5f, 0.8660254038f};
    const float SIN6[12] = {0.f, 0.5f, 0.8660254038f, 1.f, 0.8660254038f, 0.5f,
                            0.f, -0.5f, -0.8660254038f, -1.f, -0.8660254038f, -0.5f};
    const int gid = blockIdx.x * blockDim.x + threadIdx.x;
    if (gid >= TBL_ROWS * NUM_CH) return;
    const int c   = gid & 63;
    const int row = gid >> 6;
    const int slo = (row & 15) - 5;
    const int cls = row >> 4;

    float s0 = 0.f, sc = 0.f, ss = 0.f;
    #pragma unroll
    for (int i = 0; i < 12; ++i) {
        const int s = slo + i;
        if (s >= 0 && s < 16) {
            const float w = W[((cls << 4) + s) * NUM_CH + c];
            s0 += w;
            sc = fmaf(w, COS6[i], sc);
            ss = fmaf(w, SIN6[i], ss);
        }
    }
    float* r = T + row * ROW_F32;
    r[c]       = 0.5f * s0;
    r[64 + c]  = 0.5f * sc;
    r[128 + c] = 0.5f * ss;
}

// ---- kernel 2 (phase A): per-edge meta -> packed {row, theta_revs} ----
__global__ __launch_bounds__(256)
void edge_meta_kernel(const int* __restrict__ atom_types,
                      const int* __restrict__ edge_src,
                      const int* __restrict__ edge_dst,
                      const float* __restrict__ norm_length,
                      uint2* __restrict__ meta,
                      int n_edges, int n_pad)
{
    const int stride = gridDim.x * blockDim.x;
    for (int e = blockIdx.x * blockDim.x + threadIdx.x; e < n_pad; e += stride) {
        uint2 mv = {0u, 0u};
        if (e < n_edges) {
            const int et  = atom_types[edge_src[e]] * NUM_TYPES + atom_types[edge_dst[e]];
            const float t = norm_length[e] * 15.0f;          // t = x/h, h = 1/15
            const int slo = (int)t - 5;                      // in [-5..10]
            mv.x = (unsigned)((et << 4) + slo + 5);          // table row 0..255
            mv.y = __float_as_uint((t - (float)slo) * (1.0f / 12.0f));  // theta (revs)
        }
        meta[e] = mv;
    }
}

// ---- kernel 3 (phase B): pure stream: meta -> table -> nt-store out ----
__global__ __launch_bounds__(256, 4)
void spline_eval_kernel(const uint2* __restrict__ meta,
                        const float4* __restrict__ tbl,
                        float* __restrict__ out,
                        int n_edges)
{
    const int lane = threadIdx.x & 63;
    const int g    = lane >> 4;          // edge-in-step 0..3
    const int q    = lane & 15;          // channel quad: channels q*4..q*4+3

    const int waves_per_block = blockDim.x >> 6;
    const int gwave  = blockIdx.x * waves_per_block + (threadIdx.x >> 6);
    const int nwaves = gridDim.x * waves_per_block;
    const int nchunks = (n_edges + 63) >> 6;

    for (int chunk = gwave; chunk < nchunks; chunk += nwaves) {
        const int e0 = chunk << 6;
        const uint2* mp = meta + e0;

        #pragma unroll 4
        for (int k = 0; k < 16; ++k) {
            const int idx = (k << 2) + g;
            const int e   = e0 + idx;
            const uint2 m = mp[idx];               // 4 distinct addrs/wave (broadcast)
            const float r = __uint_as_float(m.y);

            float cs, sn;
            asm("v_cos_f32 %0, %1" : "=v"(cs) : "v"(r));
            asm("v_sin_f32 %0, %1" : "=v"(sn) : "v"(r));

            const float4* rp = tbl + ((int)m.x * 48 + q);
            const float4 a = rp[0];     // T0
            const float4 b = rp[16];    // TC
            const float4 c = rp[32];    // TS

            vfloat4 o;
            o.x = fmaf(sn, c.x, fmaf(cs, b.x, a.x));
            o.y = fmaf(sn, c.y, fmaf(cs, b.y, a.y));
            o.z = fmaf(sn, c.z, fmaf(cs, b.z, a.z));
            o.w = fmaf(sn, c.w, fmaf(cs, b.w, a.w));

            if (e < n_edges) {
                vfloat4* po = reinterpret_cast<vfloat4*>(out + (size_t)e * NUM_CH + (q << 2));
                __builtin_nontemporal_store(o, po);   // bypass L2: out is never re-read
            }
        }
    }
}

extern "C" void kernel_launch(void* const* d_in, const int* in_sizes, int n_in,
                              void* d_out, int out_size, void* d_ws, size_t ws_size,
                              hipStream_t stream)
{
    const int*   atom_types   = (const int*)d_in[0];
    const int*   edge_index   = (const int*)d_in[1];
    const float* norm_length  = (const float*)d_in[2];
    const float* class_weight = (const float*)d_in[3];
    float*       out          = (float*)d_out;

    const int n_edges   = in_sizes[2];           // |norm_length| = E
    const int* edge_src = edge_index;            // row 0 of [2, E]
    const int* edge_dst = edge_index + n_edges;  // row 1

    const int nchunks = (n_edges + 63) >> 6;
    const int n_pad   = nchunks << 6;

    float* tbl  = (float*)d_ws;                           // 192 KB table
    uint2* meta = (uint2*)((char*)d_ws + (1 << 20));      // 16 MB packed meta

    hipLaunchKernelGGL(build_table_kernel, dim3(64), dim3(256), 0, stream,
                       class_weight, tbl);
    hipLaunchKernelGGL(edge_meta_kernel, dim3(2048), dim3(256), 0, stream,
                       atom_types, edge_src, edge_dst, norm_length,
                       meta, n_edges, n_pad);
    hipLaunchKernelGGL(spline_eval_kernel, dim3(4096), dim3(256), 0, stream,
                       meta, (const float4*)tbl, out, n_edges);
}